// Round 1
// baseline (405.407 us; speedup 1.0000x reference)
//
#include <hip/hip_runtime.h>
#include <hip/hip_bf16.h>
#include <math.h>

#define IN_DIM 128
#define C_DIM 64

// ---------------------------------------------------------------------------
// Kernel 1: g = x @ W  (N x 128 @ 128 x 64), fused with per-node score dots:
//   s_i[n] = g[n,:]·att_i + corrs[n,:]·att_em_i
//   s_j[n] = g[n,:]·att_j + corrs[n,:]·att_em_j
// One wave per row; lane c owns output channel c. W staged in LDS (32 KB).
// ---------------------------------------------------------------------------
__global__ __launch_bounds__(256) void k_gemm_scores(
    const float* __restrict__ x, const float* __restrict__ W,
    const float* __restrict__ corrs,
    const float* __restrict__ att_i, const float* __restrict__ att_j,
    const float* __restrict__ att_em_i, const float* __restrict__ att_em_j,
    float* __restrict__ g, float* __restrict__ s_i, float* __restrict__ s_j,
    int N)
{
    __shared__ float Wl[IN_DIM * C_DIM];   // 32 KB
    int tid = threadIdx.x;
    for (int i = tid; i < IN_DIM * C_DIM; i += 256) Wl[i] = W[i];
    __syncthreads();

    int wave = tid >> 6, lane = tid & 63;
    const int ROWS_PER_BLOCK = 32;        // 8 rows per wave
    int row0 = blockIdx.x * ROWS_PER_BLOCK;

    for (int r = wave; r < ROWS_PER_BLOCK; r += 4) {
        int row = row0 + r;
        if (row >= N) break;

        float xa = x[(size_t)row * IN_DIM + lane];
        float xb = x[(size_t)row * IN_DIM + 64 + lane];
        float acc = 0.f;
#pragma unroll
        for (int k = 0; k < 64; ++k) {
            float xk = __shfl(xa, k);
            acc = fmaf(xk, Wl[k * C_DIM + lane], acc);
        }
#pragma unroll
        for (int k = 0; k < 64; ++k) {
            float xk = __shfl(xb, k);
            acc = fmaf(xk, Wl[(64 + k) * C_DIM + lane], acc);
        }
        g[(size_t)row * C_DIM + lane] = acc;

        float cr = corrs[(size_t)row * 64 + lane];
        float vi = acc * att_i[lane] + cr * att_em_i[lane];
        float vj = acc * att_j[lane] + cr * att_em_j[lane];
#pragma unroll
        for (int o = 32; o > 0; o >>= 1) {
            vi += __shfl_xor(vi, o);
            vj += __shfl_xor(vj, o);
        }
        if (lane == 0) { s_i[row] = vi; s_j[row] = vj; }
    }
}

// ---------------------------------------------------------------------------
// CSR build: deg init (=1 for the self loop), count, scan, fill
// ---------------------------------------------------------------------------
__global__ void k_init_deg(int* __restrict__ deg, int N) {
    int i = blockIdx.x * blockDim.x + threadIdx.x;
    if (i < N) deg[i] = 1;
}

__global__ void k_count(const int* __restrict__ dst, int E, int* __restrict__ deg) {
    int i = blockIdx.x * blockDim.x + threadIdx.x;
    if (i < E) atomicAdd(&deg[dst[i]], 1);
}

__global__ __launch_bounds__(1024) void k_scan(
    const int* __restrict__ deg, int* __restrict__ row_ptr,
    int* __restrict__ cursor, int N)
{
    __shared__ int sh[1024];
    int t = threadIdx.x;
    int CH = (N + 1023) / 1024;
    int b = t * CH;
    int e = min(b + CH, N);
    int sum = 0;
    for (int i = b; i < e; ++i) sum += deg[i];
    sh[t] = sum;
    __syncthreads();
    for (int off = 1; off < 1024; off <<= 1) {
        int v = (t >= off) ? sh[t - off] : 0;
        __syncthreads();
        sh[t] += v;
        __syncthreads();
    }
    int total = sh[1023];
    int run = sh[t] - sum;                 // exclusive prefix
    for (int i = b; i < e; ++i) {
        row_ptr[i] = run;
        cursor[i]  = run;
        run += deg[i];
    }
    if (t == 0) row_ptr[N] = total;
}

__global__ void k_fill(const int* __restrict__ src, const int* __restrict__ dst,
                       int E, int N, int* __restrict__ cursor,
                       int* __restrict__ edge_src)
{
    int i = blockIdx.x * blockDim.x + threadIdx.x;
    if (i < E) {
        int d = dst[i];
        int p = atomicAdd(&cursor[d], 1);
        edge_src[p] = src[i];
    } else if (i < E + N) {
        int n = i - E;
        int p = atomicAdd(&cursor[n], 1);
        edge_src[p] = n;                   // self loop
    }
}

// ---------------------------------------------------------------------------
// Kernel 6: per-node softmax + aggregate. One wave per node.
// Pass A: lane-parallel online (max, expsum) over incoming edges, xor-combine.
// Pass B: serial edge loop; all lanes share scalar weight, lane c = channel c
//         accumulates w * g[src][c] (coalesced 256B row gathers).
// ---------------------------------------------------------------------------
__global__ __launch_bounds__(256) void k_aggregate(
    const float* __restrict__ g, const float* __restrict__ s_i,
    const float* __restrict__ s_j,
    const int* __restrict__ row_ptr, const int* __restrict__ edge_src,
    const float* __restrict__ bias, float* __restrict__ out, int N)
{
    int wave = threadIdx.x >> 6, lane = threadIdx.x & 63;
    int n = blockIdx.x * 4 + wave;
    if (n >= N) return;

    int start = row_ptr[n];
    int end   = row_ptr[n + 1];
    float si  = s_i[n];

    // --- online max + expsum, lane-parallel over edges ---
    float m = -1e30f, ssum = 0.f;
    for (int e0 = start; e0 < end; e0 += 64) {
        int e = e0 + lane;
        if (e < end) {
            int srcn = edge_src[e];
            float a = si + s_j[srcn];
            a = (a > 0.f) ? a : 0.2f * a;
            float nm = fmaxf(m, a);
            ssum = ssum * __expf(m - nm) + __expf(a - nm);
            m = nm;
        }
    }
#pragma unroll
    for (int o = 32; o > 0; o >>= 1) {
        float mo = __shfl_xor(m, o);
        float so = __shfl_xor(ssum, o);
        float nm = fmaxf(m, mo);
        ssum = ssum * __expf(m - nm) + so * __expf(mo - nm);
        m = nm;
    }
    float inv_denom = 1.f / (ssum + 1e-16f);

    // --- weighted aggregation; lane c owns channel c ---
    float acc = 0.f;
    for (int e = start; e < end; ++e) {
        int srcn = edge_src[e];            // wave-uniform broadcast load
        float a = si + s_j[srcn];
        a = (a > 0.f) ? a : 0.2f * a;
        float w = __expf(a - m) * inv_denom;
        acc = fmaf(w, g[(size_t)srcn * C_DIM + lane], acc);
    }
    float o = acc + bias[lane];
    out[(size_t)n * C_DIM + lane] = fmaxf(o, 0.f);
}

// ---------------------------------------------------------------------------
extern "C" void kernel_launch(void* const* d_in, const int* in_sizes, int n_in,
                              void* d_out, int out_size, void* d_ws, size_t ws_size,
                              hipStream_t stream)
{
    const float* x        = (const float*)d_in[0];
    const int*   eidx     = (const int*)  d_in[1];
    const float* corrs    = (const float*)d_in[2];
    const float* W        = (const float*)d_in[3];
    const float* att_i    = (const float*)d_in[4];
    const float* att_j    = (const float*)d_in[5];
    const float* att_em_i = (const float*)d_in[6];
    const float* att_em_j = (const float*)d_in[7];
    const float* bias     = (const float*)d_in[8];
    float* out = (float*)d_out;

    int N = in_sizes[0] / IN_DIM;
    int E = in_sizes[1] / 2;
    const int* src = eidx;
    const int* dst = eidx + E;

    char* ws = (char*)d_ws;
    size_t off = 0;
    auto alloc = [&](size_t bytes) -> void* {
        void* p = ws + off;
        off += (bytes + 255) & ~(size_t)255;
        return p;
    };
    float* g        = (float*)alloc((size_t)N * C_DIM * sizeof(float));
    float* s_i      = (float*)alloc((size_t)N * sizeof(float));
    float* s_j      = (float*)alloc((size_t)N * sizeof(float));
    int*   deg      = (int*)  alloc((size_t)N * sizeof(int));
    int*   row_ptr  = (int*)  alloc((size_t)(N + 1) * sizeof(int));
    int*   cursor   = (int*)  alloc((size_t)N * sizeof(int));
    int*   edge_src = (int*)  alloc((size_t)(E + N) * sizeof(int));
    (void)ws_size; (void)n_in; (void)out_size;

    k_gemm_scores<<<(N + 31) / 32, 256, 0, stream>>>(
        x, W, corrs, att_i, att_j, att_em_i, att_em_j, g, s_i, s_j, N);

    k_init_deg<<<(N + 255) / 256, 256, 0, stream>>>(deg, N);
    k_count   <<<(E + 255) / 256, 256, 0, stream>>>(dst, E, deg);
    k_scan    <<<1, 1024, 0, stream>>>(deg, row_ptr, cursor, N);
    k_fill    <<<(E + N + 255) / 256, 256, 0, stream>>>(src, dst, E, N, cursor, edge_src);

    k_aggregate<<<(N + 3) / 4, 256, 0, stream>>>(
        g, s_i, s_j, row_ptr, edge_src, bias, out, N);
}

// Round 2
// 311.415 us; speedup vs baseline: 1.3018x; 1.3018x over previous
//
#include <hip/hip_runtime.h>
#include <hip/hip_bf16.h>
#include <math.h>

#define IN_DIM 128
#define C_DIM 64

typedef short bf16x8 __attribute__((ext_vector_type(8)));
typedef float f32x4 __attribute__((ext_vector_type(4)));

static __device__ __forceinline__ unsigned short f2bf(float f) {
    unsigned int u = __float_as_uint(f);
    u += 0x7FFFu + ((u >> 16) & 1u);          // round-to-nearest-even
    return (unsigned short)(u >> 16);
}
static __device__ __forceinline__ float bf2f(unsigned short h) {
    return __uint_as_float(((unsigned int)h) << 16);
}

// ---------------------------------------------------------------------------
// Kernel 1: g = x @ W via bf16 MFMA with 3-term error split, fused scores.
// Block = 256 thr (4 waves), 64 rows x 64 cols per block, K=128 in 4 steps.
// W staged once per block to LDS as hi/lo bf16, XOR-swizzled (conflict-free).
// A-frags loaded straight from global (each x element read exactly once).
// A/B use the same (lane>>4)*8+e k-ordering -> correct for any HW k-perm.
// C/D layout (verified): col = lane&15, row = (lane>>4)*4 + reg.
// ---------------------------------------------------------------------------
__global__ __launch_bounds__(256) void k_mfma_scores(
    const float* __restrict__ x, const float* __restrict__ W,
    const float* __restrict__ corrs,
    const float* __restrict__ att_i, const float* __restrict__ att_j,
    const float* __restrict__ att_em_i, const float* __restrict__ att_em_j,
    float* __restrict__ g, float* __restrict__ s_i, float* __restrict__ s_j,
    int N)
{
    __shared__ __attribute__((aligned(16))) unsigned short WT[2][64][128]; // 32KB

    int tid = threadIdx.x;
    // ---- stage W -> LDS transposed, split hi/lo, swizzled: idx k^((c&7)<<3)
#pragma unroll
    for (int p = 0; p < 8; ++p) {
        int f = p * 1024 + tid * 4;               // flat into W[128][64]
        f32x4 w4 = *(const f32x4*)(W + f);
        int k  = f >> 6;
        int c0 = f & 63;
#pragma unroll
        for (int i = 0; i < 4; ++i) {
            int c = c0 + i;
            float wv = w4[i];
            unsigned short hi = f2bf(wv);
            unsigned short lo = f2bf(wv - bf2f(hi));
            int ks = k ^ ((c & 7) << 3);
            WT[0][c][ks] = hi;
            WT[1][c][ks] = lo;
        }
    }
    __syncthreads();

    int wv = tid >> 6, lane = tid & 63;
    int mrow = lane & 15;          // A row / B col / C col index
    int kgrp = lane >> 4;          // 0..3
    int row  = blockIdx.x * 64 + wv * 16 + mrow;
    int rowc = min(row, N - 1);

    f32x4 acc[4];
#pragma unroll
    for (int t = 0; t < 4; ++t) { f32x4 z = {0.f, 0.f, 0.f, 0.f}; acc[t] = z; }

#pragma unroll
    for (int s = 0; s < 4; ++s) {
        const float* xp = x + (size_t)rowc * IN_DIM + s * 32 + kgrp * 8;
        f32x4 xa = *(const f32x4*)xp;
        f32x4 xb = *(const f32x4*)(xp + 4);
        bf16x8 ah, al;
#pragma unroll
        for (int i = 0; i < 4; ++i) {
            unsigned short h0 = f2bf(xa[i]);
            ah[i]     = (short)h0;
            al[i]     = (short)f2bf(xa[i] - bf2f(h0));
            unsigned short h1 = f2bf(xb[i]);
            ah[4 + i] = (short)h1;
            al[4 + i] = (short)f2bf(xb[i] - bf2f(h1));
        }
        int kbase = s * 32 + kgrp * 8;
#pragma unroll
        for (int t = 0; t < 4; ++t) {
            int c  = t * 16 + mrow;
            int ks = kbase ^ ((c & 7) << 3);
            bf16x8 bh = *(const bf16x8*)&WT[0][c][ks];
            bf16x8 bl = *(const bf16x8*)&WT[1][c][ks];
            acc[t] = __builtin_amdgcn_mfma_f32_16x16x32_bf16(ah, bh, acc[t], 0, 0, 0);
            acc[t] = __builtin_amdgcn_mfma_f32_16x16x32_bf16(ah, bl, acc[t], 0, 0, 0);
            acc[t] = __builtin_amdgcn_mfma_f32_16x16x32_bf16(al, bh, acc[t], 0, 0, 0);
        }
    }

    // ---- epilogue: write g, compute per-row score dots s_i/s_j
    float ai[4], aj[4], aei[4], aej[4];
#pragma unroll
    for (int t = 0; t < 4; ++t) {
        ai[t]  = att_i[t * 16 + mrow];
        aj[t]  = att_j[t * 16 + mrow];
        aei[t] = att_em_i[t * 16 + mrow];
        aej[t] = att_em_j[t * 16 + mrow];
    }
    int crow_base = blockIdx.x * 64 + wv * 16 + (lane >> 4) * 4;
#pragma unroll
    for (int r = 0; r < 4; ++r) {
        int grow  = crow_base + r;
        int growc = min(grow, N - 1);
        float vi = 0.f, vj = 0.f;
#pragma unroll
        for (int t = 0; t < 4; ++t) {
            float gv = acc[t][r];
            float cv = corrs[(size_t)growc * 64 + t * 16 + mrow];
            if (grow < N) g[(size_t)grow * C_DIM + t * 16 + mrow] = gv;
            vi = fmaf(gv, ai[t], fmaf(cv, aei[t], vi));
            vj = fmaf(gv, aj[t], fmaf(cv, aej[t], vj));
        }
#pragma unroll
        for (int o = 1; o < 16; o <<= 1) {
            vi += __shfl_xor(vi, o);
            vj += __shfl_xor(vj, o);
        }
        if (mrow == 0 && grow < N) { s_i[grow] = vi; s_j[grow] = vj; }
    }
}

// ---------------------------------------------------------------------------
// CSR build: deg init (=1 for the self loop), count, scan, fill
// ---------------------------------------------------------------------------
__global__ void k_init_deg(int* __restrict__ deg, int N) {
    int i = blockIdx.x * blockDim.x + threadIdx.x;
    if (i < N) deg[i] = 1;
}

__global__ void k_count(const int* __restrict__ dst, int E, int* __restrict__ deg) {
    int i = blockIdx.x * blockDim.x + threadIdx.x;
    if (i < E) atomicAdd(&deg[dst[i]], 1);
}

__global__ __launch_bounds__(1024) void k_scan(
    const int* __restrict__ deg, int* __restrict__ row_ptr,
    int* __restrict__ cursor, int N)
{
    __shared__ int sh[1024];
    int t = threadIdx.x;
    int CH = (N + 1023) / 1024;
    int b = t * CH;
    int e = min(b + CH, N);
    int sum = 0;
    for (int i = b; i < e; ++i) sum += deg[i];
    sh[t] = sum;
    __syncthreads();
    for (int off = 1; off < 1024; off <<= 1) {
        int v = (t >= off) ? sh[t - off] : 0;
        __syncthreads();
        sh[t] += v;
        __syncthreads();
    }
    int total = sh[1023];
    int run = sh[t] - sum;                 // exclusive prefix
    for (int i = b; i < e; ++i) {
        row_ptr[i] = run;
        cursor[i]  = run;
        run += deg[i];
    }
    if (t == 0) row_ptr[N] = total;
}

__global__ void k_fill(const int* __restrict__ src, const int* __restrict__ dst,
                       int E, int N, int* __restrict__ cursor,
                       int* __restrict__ edge_src)
{
    int i = blockIdx.x * blockDim.x + threadIdx.x;
    if (i < E) {
        int d = dst[i];
        int p = atomicAdd(&cursor[d], 1);
        edge_src[p] = src[i];
    } else if (i < E + N) {
        int n = i - E;
        int p = atomicAdd(&cursor[n], 1);
        edge_src[p] = n;                   // self loop
    }
}

// ---------------------------------------------------------------------------
// Per-node softmax + aggregate. One wave per node.
// ---------------------------------------------------------------------------
__global__ __launch_bounds__(256) void k_aggregate(
    const float* __restrict__ g, const float* __restrict__ s_i,
    const float* __restrict__ s_j,
    const int* __restrict__ row_ptr, const int* __restrict__ edge_src,
    const float* __restrict__ bias, float* __restrict__ out, int N)
{
    int wave = threadIdx.x >> 6, lane = threadIdx.x & 63;
    int n = blockIdx.x * 4 + wave;
    if (n >= N) return;

    int start = row_ptr[n];
    int end   = row_ptr[n + 1];
    float si  = s_i[n];

    // --- online max + expsum, lane-parallel over edges ---
    float m = -1e30f, ssum = 0.f;
    for (int e0 = start; e0 < end; e0 += 64) {
        int e = e0 + lane;
        if (e < end) {
            int srcn = edge_src[e];
            float a = si + s_j[srcn];
            a = (a > 0.f) ? a : 0.2f * a;
            float nm = fmaxf(m, a);
            ssum = ssum * __expf(m - nm) + __expf(a - nm);
            m = nm;
        }
    }
#pragma unroll
    for (int o = 32; o > 0; o >>= 1) {
        float mo = __shfl_xor(m, o);
        float so = __shfl_xor(ssum, o);
        float nm = fmaxf(m, mo);
        ssum = ssum * __expf(m - nm) + so * __expf(mo - nm);
        m = nm;
    }
    float inv_denom = 1.f / (ssum + 1e-16f);

    // --- weighted aggregation; lane c owns channel c ---
    float acc = 0.f;
    for (int e = start; e < end; ++e) {
        int srcn = edge_src[e];            // wave-uniform broadcast load
        float a = si + s_j[srcn];
        a = (a > 0.f) ? a : 0.2f * a;
        float w = __expf(a - m) * inv_denom;
        acc = fmaf(w, g[(size_t)srcn * C_DIM + lane], acc);
    }
    float o = acc + bias[lane];
    out[(size_t)n * C_DIM + lane] = fmaxf(o, 0.f);
}

// ---------------------------------------------------------------------------
extern "C" void kernel_launch(void* const* d_in, const int* in_sizes, int n_in,
                              void* d_out, int out_size, void* d_ws, size_t ws_size,
                              hipStream_t stream)
{
    const float* x        = (const float*)d_in[0];
    const int*   eidx     = (const int*)  d_in[1];
    const float* corrs    = (const float*)d_in[2];
    const float* W        = (const float*)d_in[3];
    const float* att_i    = (const float*)d_in[4];
    const float* att_j    = (const float*)d_in[5];
    const float* att_em_i = (const float*)d_in[6];
    const float* att_em_j = (const float*)d_in[7];
    const float* bias     = (const float*)d_in[8];
    float* out = (float*)d_out;

    int N = in_sizes[0] / IN_DIM;
    int E = in_sizes[1] / 2;
    const int* src = eidx;
    const int* dst = eidx + E;

    char* ws = (char*)d_ws;
    size_t off = 0;
    auto alloc = [&](size_t bytes) -> void* {
        void* p = ws + off;
        off += (bytes + 255) & ~(size_t)255;
        return p;
    };
    float* g        = (float*)alloc((size_t)N * C_DIM * sizeof(float));
    float* s_i      = (float*)alloc((size_t)N * sizeof(float));
    float* s_j      = (float*)alloc((size_t)N * sizeof(float));
    int*   deg      = (int*)  alloc((size_t)N * sizeof(int));
    int*   row_ptr  = (int*)  alloc((size_t)(N + 1) * sizeof(int));
    int*   cursor   = (int*)  alloc((size_t)N * sizeof(int));
    int*   edge_src = (int*)  alloc((size_t)(E + N) * sizeof(int));
    (void)ws_size; (void)n_in; (void)out_size;

    k_mfma_scores<<<(N + 63) / 64, 256, 0, stream>>>(
        x, W, corrs, att_i, att_j, att_em_i, att_em_j, g, s_i, s_j, N);

    k_init_deg<<<(N + 255) / 256, 256, 0, stream>>>(deg, N);
    k_count   <<<(E + 255) / 256, 256, 0, stream>>>(dst, E, deg);
    k_scan    <<<1, 1024, 0, stream>>>(deg, row_ptr, cursor, N);
    k_fill    <<<(E + N + 255) / 256, 256, 0, stream>>>(src, dst, E, N, cursor, edge_src);

    k_aggregate<<<(N + 3) / 4, 256, 0, stream>>>(
        g, s_i, s_j, row_ptr, edge_src, bias, out, N);
}

// Round 4
// 210.370 us; speedup vs baseline: 1.9271x; 1.4803x over previous
//
#include <hip/hip_runtime.h>
#include <hip/hip_bf16.h>
#include <math.h>

#define IN_DIM 128
#define C_DIM 64

typedef short bf16x8 __attribute__((ext_vector_type(8)));
typedef float f32x4 __attribute__((ext_vector_type(4)));

static __device__ __forceinline__ unsigned short f2bf(float f) {
    unsigned int u = __float_as_uint(f);
    u += 0x7FFFu + ((u >> 16) & 1u);          // round-to-nearest-even
    return (unsigned short)(u >> 16);
}
static __device__ __forceinline__ float bf2f(unsigned short h) {
    return __uint_as_float(((unsigned int)h) << 16);
}

// ---------------------------------------------------------------------------
// Kernel 1: g = x @ W via bf16 MFMA with 3-term error split, fused scores.
// (unchanged from R2 — 64x64 tile/block, W hi/lo in LDS, swizzled)
// ---------------------------------------------------------------------------
__global__ __launch_bounds__(256) void k_mfma_scores(
    const float* __restrict__ x, const float* __restrict__ W,
    const float* __restrict__ corrs,
    const float* __restrict__ att_i, const float* __restrict__ att_j,
    const float* __restrict__ att_em_i, const float* __restrict__ att_em_j,
    float* __restrict__ g, float* __restrict__ s_i, float* __restrict__ s_j,
    int N)
{
    __shared__ __attribute__((aligned(16))) unsigned short WT[2][64][128]; // 32KB

    int tid = threadIdx.x;
#pragma unroll
    for (int p = 0; p < 8; ++p) {
        int f = p * 1024 + tid * 4;               // flat into W[128][64]
        f32x4 w4 = *(const f32x4*)(W + f);
        int k  = f >> 6;
        int c0 = f & 63;
#pragma unroll
        for (int i = 0; i < 4; ++i) {
            int c = c0 + i;
            float wv = w4[i];
            unsigned short hi = f2bf(wv);
            unsigned short lo = f2bf(wv - bf2f(hi));
            int ks = k ^ ((c & 7) << 3);
            WT[0][c][ks] = hi;
            WT[1][c][ks] = lo;
        }
    }
    __syncthreads();

    int wv = tid >> 6, lane = tid & 63;
    int mrow = lane & 15;
    int kgrp = lane >> 4;
    int row  = blockIdx.x * 64 + wv * 16 + mrow;
    int rowc = min(row, N - 1);

    f32x4 acc[4];
#pragma unroll
    for (int t = 0; t < 4; ++t) { f32x4 z = {0.f, 0.f, 0.f, 0.f}; acc[t] = z; }

#pragma unroll
    for (int s = 0; s < 4; ++s) {
        const float* xp = x + (size_t)rowc * IN_DIM + s * 32 + kgrp * 8;
        f32x4 xa = *(const f32x4*)xp;
        f32x4 xb = *(const f32x4*)(xp + 4);
        bf16x8 ah, al;
#pragma unroll
        for (int i = 0; i < 4; ++i) {
            unsigned short h0 = f2bf(xa[i]);
            ah[i]     = (short)h0;
            al[i]     = (short)f2bf(xa[i] - bf2f(h0));
            unsigned short h1 = f2bf(xb[i]);
            ah[4 + i] = (short)h1;
            al[4 + i] = (short)f2bf(xb[i] - bf2f(h1));
        }
        int kbase = s * 32 + kgrp * 8;
#pragma unroll
        for (int t = 0; t < 4; ++t) {
            int c  = t * 16 + mrow;
            int ks = kbase ^ ((c & 7) << 3);
            bf16x8 bh = *(const bf16x8*)&WT[0][c][ks];
            bf16x8 bl = *(const bf16x8*)&WT[1][c][ks];
            acc[t] = __builtin_amdgcn_mfma_f32_16x16x32_bf16(ah, bh, acc[t], 0, 0, 0);
            acc[t] = __builtin_amdgcn_mfma_f32_16x16x32_bf16(ah, bl, acc[t], 0, 0, 0);
            acc[t] = __builtin_amdgcn_mfma_f32_16x16x32_bf16(al, bh, acc[t], 0, 0, 0);
        }
    }

    float ai[4], aj[4], aei[4], aej[4];
#pragma unroll
    for (int t = 0; t < 4; ++t) {
        ai[t]  = att_i[t * 16 + mrow];
        aj[t]  = att_j[t * 16 + mrow];
        aei[t] = att_em_i[t * 16 + mrow];
        aej[t] = att_em_j[t * 16 + mrow];
    }
    int crow_base = blockIdx.x * 64 + wv * 16 + (lane >> 4) * 4;
#pragma unroll
    for (int r = 0; r < 4; ++r) {
        int grow  = crow_base + r;
        int growc = min(grow, N - 1);
        float vi = 0.f, vj = 0.f;
#pragma unroll
        for (int t = 0; t < 4; ++t) {
            float gv = acc[t][r];
            float cv = corrs[(size_t)growc * 64 + t * 16 + mrow];
            if (grow < N) g[(size_t)grow * C_DIM + t * 16 + mrow] = gv;
            vi = fmaf(gv, ai[t], fmaf(cv, aei[t], vi));
            vj = fmaf(gv, aj[t], fmaf(cv, aej[t], vj));
        }
#pragma unroll
        for (int o = 1; o < 16; o <<= 1) {
            vi += __shfl_xor(vi, o);
            vj += __shfl_xor(vj, o);
        }
        if (mrow == 0 && grow < N) { s_i[grow] = vi; s_j[grow] = vj; }
    }
}

// ---------------------------------------------------------------------------
// CSR build: deg init (=1 self loop), count, hierarchical scan, fill
// ---------------------------------------------------------------------------
__global__ void k_init_deg(int* __restrict__ deg, int N) {
    int i = blockIdx.x * blockDim.x + threadIdx.x;
    if (i < N) deg[i] = 1;
}

__global__ void k_count(const int* __restrict__ dst, int E, int* __restrict__ deg) {
    int i = blockIdx.x * blockDim.x + threadIdx.x;
    if (i < E) atomicAdd(&deg[dst[i]], 1);
}

// Phase 1: per-block (1024 elems) sum
__global__ __launch_bounds__(256) void k_scan_part(
    const int* __restrict__ deg, int* __restrict__ bsum, int N)
{
    int b = blockIdx.x, t = threadIdx.x;
    int base = b * 1024 + t * 4;
    int s = 0;
    if (base + 3 < N) {
        const int4 v = *(const int4*)(deg + base);
        s = v.x + v.y + v.z + v.w;
    } else {
        for (int i = 0; i < 4; ++i) if (base + i < N) s += deg[base + i];
    }
#pragma unroll
    for (int o = 1; o < 64; o <<= 1) s += __shfl_xor(s, o);
    __shared__ int ws[4];
    if ((t & 63) == 0) ws[t >> 6] = s;
    __syncthreads();
    if (t == 0) bsum[b] = ws[0] + ws[1] + ws[2] + ws[3];
}

// Phase 2: one wave scans the block sums (nb ~ 49), in-place -> exclusive
__global__ void k_scan_bsum(int* __restrict__ bsum, int nb, int* __restrict__ rowptr_tail)
{
    int lane = threadIdx.x;
    int carry = 0;
    for (int b0 = 0; b0 < nb; b0 += 64) {
        int i = b0 + lane;
        int orig = (i < nb) ? bsum[i] : 0;
        int v = orig;
#pragma unroll
        for (int o = 1; o < 64; o <<= 1) {
            int u = __shfl_up(v, o);
            if (lane >= o) v += u;
        }
        if (i < nb) bsum[i] = carry + v - orig;   // exclusive
        carry += __shfl(v, 63);
    }
    if (lane == 0) *rowptr_tail = carry;          // row_ptr[N] = total
}

// Phase 3: local exclusive scan + block offset -> row_ptr / cursor
__global__ __launch_bounds__(256) void k_scan_final(
    const int* __restrict__ deg, const int* __restrict__ bsum,
    int* __restrict__ row_ptr, int* __restrict__ cursor, int N)
{
    int b = blockIdx.x, t = threadIdx.x;
    int base = b * 1024 + t * 4;
    int v[4];
    int s = 0;
#pragma unroll
    for (int i = 0; i < 4; ++i) {
        v[i] = (base + i < N) ? deg[base + i] : 0;
        s += v[i];
    }
    int lane = t & 63, wv = t >> 6;
    int inc = s;
#pragma unroll
    for (int o = 1; o < 64; o <<= 1) {
        int u = __shfl_up(inc, o);
        if (lane >= o) inc += u;
    }
    __shared__ int wsum[4];
    if (lane == 63) wsum[wv] = inc;
    __syncthreads();
    int woff = 0;
    for (int w = 0; w < wv; ++w) woff += wsum[w];
    int run = bsum[b] + woff + inc - s;            // exclusive prefix
#pragma unroll
    for (int i = 0; i < 4; ++i) {
        if (base + i < N) { row_ptr[base + i] = run; cursor[base + i] = run; }
        run += v[i];
    }
}

__global__ void k_fill(const int* __restrict__ src, const int* __restrict__ dst,
                       int E, int N, int* __restrict__ cursor,
                       int* __restrict__ edge_src)
{
    int i = blockIdx.x * blockDim.x + threadIdx.x;
    if (i < E) {
        int d = dst[i];
        int p = atomicAdd(&cursor[d], 1);
        edge_src[p] = src[i];
    } else if (i < E + N) {
        int n = i - E;
        int p = atomicAdd(&cursor[n], 1);
        edge_src[p] = n;                   // self loop
    }
}

// ---------------------------------------------------------------------------
// Per-node softmax + aggregate. One wave per node.
// ---------------------------------------------------------------------------
__global__ __launch_bounds__(256) void k_aggregate(
    const float* __restrict__ g, const float* __restrict__ s_i,
    const float* __restrict__ s_j,
    const int* __restrict__ row_ptr, const int* __restrict__ edge_src,
    const float* __restrict__ bias, float* __restrict__ out, int N)
{
    int wave = threadIdx.x >> 6, lane = threadIdx.x & 63;
    int n = blockIdx.x * 4 + wave;
    if (n >= N) return;

    int start = row_ptr[n];
    int end   = row_ptr[n + 1];
    float si  = s_i[n];

    // --- online max + expsum, lane-parallel over edges ---
    float m = -1e30f, ssum = 0.f;
    for (int e0 = start; e0 < end; e0 += 64) {
        int e = e0 + lane;
        if (e < end) {
            int srcn = edge_src[e];
            float a = si + s_j[srcn];
            a = (a > 0.f) ? a : 0.2f * a;
            float nm = fmaxf(m, a);
            ssum = ssum * __expf(m - nm) + __expf(a - nm);
            m = nm;
        }
    }
#pragma unroll
    for (int o = 32; o > 0; o >>= 1) {
        float mo = __shfl_xor(m, o);
        float so = __shfl_xor(ssum, o);
        float nm = fmaxf(m, mo);
        ssum = ssum * __expf(m - nm) + so * __expf(mo - nm);
        m = nm;
    }
    float inv_denom = 1.f / (ssum + 1e-16f);

    // --- weighted aggregation; lane c owns channel c ---
    float acc = 0.f;
    for (int e = start; e < end; ++e) {
        int srcn = edge_src[e];            // wave-uniform broadcast load
        float a = si + s_j[srcn];
        a = (a > 0.f) ? a : 0.2f * a;
        float w = __expf(a - m) * inv_denom;
        acc = fmaf(w, g[(size_t)srcn * C_DIM + lane], acc);
    }
    float o = acc + bias[lane];
    out[(size_t)n * C_DIM + lane] = fmaxf(o, 0.f);
}

// ---------------------------------------------------------------------------
extern "C" void kernel_launch(void* const* d_in, const int* in_sizes, int n_in,
                              void* d_out, int out_size, void* d_ws, size_t ws_size,
                              hipStream_t stream)
{
    const float* x        = (const float*)d_in[0];
    const int*   eidx     = (const int*)  d_in[1];
    const float* corrs    = (const float*)d_in[2];
    const float* W        = (const float*)d_in[3];
    const float* att_i    = (const float*)d_in[4];
    const float* att_j    = (const float*)d_in[5];
    const float* att_em_i = (const float*)d_in[6];
    const float* att_em_j = (const float*)d_in[7];
    const float* bias     = (const float*)d_in[8];
    float* out = (float*)d_out;

    int N = in_sizes[0] / IN_DIM;
    int E = in_sizes[1] / 2;
    const int* src = eidx;
    const int* dst = eidx + E;

    char* ws = (char*)d_ws;
    size_t off = 0;
    auto alloc = [&](size_t bytes) -> void* {
        void* p = ws + off;
        off += (bytes + 255) & ~(size_t)255;
        return p;
    };
    float* g        = (float*)alloc((size_t)N * C_DIM * sizeof(float));
    float* s_i      = (float*)alloc((size_t)N * sizeof(float));
    float* s_j      = (float*)alloc((size_t)N * sizeof(float));
    int*   deg      = (int*)  alloc((size_t)N * sizeof(int));
    int*   row_ptr  = (int*)  alloc((size_t)(N + 1) * sizeof(int));
    int*   cursor   = (int*)  alloc((size_t)N * sizeof(int));
    int*   edge_src = (int*)  alloc((size_t)(E + N) * sizeof(int));
    int    nb       = (N + 1023) / 1024;
    int*   bsum     = (int*)  alloc((size_t)nb * sizeof(int));
    (void)ws_size; (void)n_in; (void)out_size;

    k_mfma_scores<<<(N + 63) / 64, 256, 0, stream>>>(
        x, W, corrs, att_i, att_j, att_em_i, att_em_j, g, s_i, s_j, N);

    k_init_deg  <<<(N + 255) / 256, 256, 0, stream>>>(deg, N);
    k_count     <<<(E + 255) / 256, 256, 0, stream>>>(dst, E, deg);
    k_scan_part <<<nb, 256, 0, stream>>>(deg, bsum, N);
    k_scan_bsum <<<1, 64, 0, stream>>>(bsum, nb, row_ptr + N);
    k_scan_final<<<nb, 256, 0, stream>>>(deg, bsum, row_ptr, cursor, N);
    k_fill      <<<(E + N + 255) / 256, 256, 0, stream>>>(src, dst, E, N, cursor, edge_src);

    k_aggregate<<<(N + 3) / 4, 256, 0, stream>>>(
        g, s_i, s_j, row_ptr, edge_src, bias, out, N);
}

// Round 5
// 158.527 us; speedup vs baseline: 2.5573x; 1.3270x over previous
//
#include <hip/hip_runtime.h>
#include <hip/hip_bf16.h>
#include <math.h>

#define IN_DIM 128
#define C_DIM 64

typedef short bf16x8 __attribute__((ext_vector_type(8)));
typedef float f32x4 __attribute__((ext_vector_type(4)));

static __device__ __forceinline__ unsigned short f2bf(float f) {
    unsigned int u = __float_as_uint(f);
    u += 0x7FFFu + ((u >> 16) & 1u);          // round-to-nearest-even
    return (unsigned short)(u >> 16);
}
static __device__ __forceinline__ float bf2f(unsigned short h) {
    return __uint_as_float(((unsigned int)h) << 16);
}

// ---------------------------------------------------------------------------
// Kernel 1: g = x @ W via bf16 MFMA (3-term split), fused score dots.
// g stored as bf16 in PERMUTED channel layout: g_bf[row*64 + mrow*4 + t]
// holds channel (t*16 + mrow)  ->  GEMM epilogue writes ushort4, aggregate
// reads ushort4 of 4 channels {cl, cl+16, cl+32, cl+48} per lane.
// ---------------------------------------------------------------------------
__global__ __launch_bounds__(256) void k_mfma_scores(
    const float* __restrict__ x, const float* __restrict__ W,
    const float* __restrict__ corrs,
    const float* __restrict__ att_i, const float* __restrict__ att_j,
    const float* __restrict__ att_em_i, const float* __restrict__ att_em_j,
    unsigned short* __restrict__ g_bf, float* __restrict__ s_i, float* __restrict__ s_j,
    int N)
{
    __shared__ __attribute__((aligned(16))) unsigned short WT[2][64][128]; // 32KB

    int tid = threadIdx.x;
#pragma unroll
    for (int p = 0; p < 8; ++p) {
        int f = p * 1024 + tid * 4;               // flat into W[128][64]
        f32x4 w4 = *(const f32x4*)(W + f);
        int k  = f >> 6;
        int c0 = f & 63;
#pragma unroll
        for (int i = 0; i < 4; ++i) {
            int c = c0 + i;
            float wv = w4[i];
            unsigned short hi = f2bf(wv);
            unsigned short lo = f2bf(wv - bf2f(hi));
            int ks = k ^ ((c & 7) << 3);
            WT[0][c][ks] = hi;
            WT[1][c][ks] = lo;
        }
    }
    __syncthreads();

    int wv = tid >> 6, lane = tid & 63;
    int mrow = lane & 15;
    int kgrp = lane >> 4;
    int row  = blockIdx.x * 64 + wv * 16 + mrow;
    int rowc = min(row, N - 1);

    f32x4 acc[4];
#pragma unroll
    for (int t = 0; t < 4; ++t) { f32x4 z = {0.f, 0.f, 0.f, 0.f}; acc[t] = z; }

#pragma unroll
    for (int s = 0; s < 4; ++s) {
        const float* xp = x + (size_t)rowc * IN_DIM + s * 32 + kgrp * 8;
        f32x4 xa = *(const f32x4*)xp;
        f32x4 xb = *(const f32x4*)(xp + 4);
        bf16x8 ah, al;
#pragma unroll
        for (int i = 0; i < 4; ++i) {
            unsigned short h0 = f2bf(xa[i]);
            ah[i]     = (short)h0;
            al[i]     = (short)f2bf(xa[i] - bf2f(h0));
            unsigned short h1 = f2bf(xb[i]);
            ah[4 + i] = (short)h1;
            al[4 + i] = (short)f2bf(xb[i] - bf2f(h1));
        }
        int kbase = s * 32 + kgrp * 8;
#pragma unroll
        for (int t = 0; t < 4; ++t) {
            int c  = t * 16 + mrow;
            int ks = kbase ^ ((c & 7) << 3);
            bf16x8 bh = *(const bf16x8*)&WT[0][c][ks];
            bf16x8 bl = *(const bf16x8*)&WT[1][c][ks];
            acc[t] = __builtin_amdgcn_mfma_f32_16x16x32_bf16(ah, bh, acc[t], 0, 0, 0);
            acc[t] = __builtin_amdgcn_mfma_f32_16x16x32_bf16(ah, bl, acc[t], 0, 0, 0);
            acc[t] = __builtin_amdgcn_mfma_f32_16x16x32_bf16(al, bh, acc[t], 0, 0, 0);
        }
    }

    float ai[4], aj[4], aei[4], aej[4];
#pragma unroll
    for (int t = 0; t < 4; ++t) {
        ai[t]  = att_i[t * 16 + mrow];
        aj[t]  = att_j[t * 16 + mrow];
        aei[t] = att_em_i[t * 16 + mrow];
        aej[t] = att_em_j[t * 16 + mrow];
    }
    int crow_base = blockIdx.x * 64 + wv * 16 + (lane >> 4) * 4;
#pragma unroll
    for (int r = 0; r < 4; ++r) {
        int grow  = crow_base + r;
        int growc = min(grow, N - 1);
        float vi = 0.f, vj = 0.f;
        ushort4 hv;
#pragma unroll
        for (int t = 0; t < 4; ++t) {
            float gv = acc[t][r];
            float cv = corrs[(size_t)growc * 64 + t * 16 + mrow];
            unsigned short h = f2bf(gv);
            if (t == 0) hv.x = h; else if (t == 1) hv.y = h;
            else if (t == 2) hv.z = h; else hv.w = h;
            vi = fmaf(gv, ai[t], fmaf(cv, aei[t], vi));
            vj = fmaf(gv, aj[t], fmaf(cv, aej[t], vj));
        }
        if (grow < N)
            *(ushort4*)(g_bf + (size_t)grow * C_DIM + mrow * 4) = hv;
#pragma unroll
        for (int o = 1; o < 16; o <<= 1) {
            vi += __shfl_xor(vi, o);
            vj += __shfl_xor(vj, o);
        }
        if (mrow == 0 && grow < N) { s_i[grow] = vi; s_j[grow] = vj; }
    }
}

// ---------------------------------------------------------------------------
// CSR build: deg init (=1 self loop), count, hierarchical scan, fill
// ---------------------------------------------------------------------------
__global__ void k_init_deg(int* __restrict__ deg, int N) {
    int i = blockIdx.x * blockDim.x + threadIdx.x;
    if (i < N) deg[i] = 1;
}

__global__ void k_count(const int* __restrict__ dst, int E, int* __restrict__ deg) {
    int i = blockIdx.x * blockDim.x + threadIdx.x;
    if (i < E) atomicAdd(&deg[dst[i]], 1);
}

__global__ __launch_bounds__(256) void k_scan_part(
    const int* __restrict__ deg, int* __restrict__ bsum, int N)
{
    int b = blockIdx.x, t = threadIdx.x;
    int base = b * 1024 + t * 4;
    int s = 0;
    if (base + 3 < N) {
        const int4 v = *(const int4*)(deg + base);
        s = v.x + v.y + v.z + v.w;
    } else {
        for (int i = 0; i < 4; ++i) if (base + i < N) s += deg[base + i];
    }
#pragma unroll
    for (int o = 1; o < 64; o <<= 1) s += __shfl_xor(s, o);
    __shared__ int ws[4];
    if ((t & 63) == 0) ws[t >> 6] = s;
    __syncthreads();
    if (t == 0) bsum[b] = ws[0] + ws[1] + ws[2] + ws[3];
}

__global__ void k_scan_bsum(int* __restrict__ bsum, int nb, int* __restrict__ rowptr_tail)
{
    int lane = threadIdx.x;
    int carry = 0;
    for (int b0 = 0; b0 < nb; b0 += 64) {
        int i = b0 + lane;
        int orig = (i < nb) ? bsum[i] : 0;
        int v = orig;
#pragma unroll
        for (int o = 1; o < 64; o <<= 1) {
            int u = __shfl_up(v, o);
            if (lane >= o) v += u;
        }
        if (i < nb) bsum[i] = carry + v - orig;   // exclusive
        carry += __shfl(v, 63);
    }
    if (lane == 0) *rowptr_tail = carry;          // row_ptr[N] = total
}

__global__ __launch_bounds__(256) void k_scan_final(
    const int* __restrict__ deg, const int* __restrict__ bsum,
    int* __restrict__ row_ptr, int* __restrict__ cursor, int N)
{
    int b = blockIdx.x, t = threadIdx.x;
    int base = b * 1024 + t * 4;
    int v[4];
    int s = 0;
#pragma unroll
    for (int i = 0; i < 4; ++i) {
        v[i] = (base + i < N) ? deg[base + i] : 0;
        s += v[i];
    }
    int lane = t & 63, wv = t >> 6;
    int inc = s;
#pragma unroll
    for (int o = 1; o < 64; o <<= 1) {
        int u = __shfl_up(inc, o);
        if (lane >= o) inc += u;
    }
    __shared__ int wsum[4];
    if (lane == 63) wsum[wv] = inc;
    __syncthreads();
    int woff = 0;
    for (int w = 0; w < wv; ++w) woff += wsum[w];
    int run = bsum[b] + woff + inc - s;            // exclusive prefix
#pragma unroll
    for (int i = 0; i < 4; ++i) {
        if (base + i < N) { row_ptr[base + i] = run; cursor[base + i] = run; }
        run += v[i];
    }
}

// Fill CSR slots; precompute per-edge leaky-relu'd score alpha in CSR order.
// s_i / s_j are 200 KB -> L2-resident gathers here.
__global__ void k_fill(const int* __restrict__ src, const int* __restrict__ dst,
                       int E, int N,
                       const float* __restrict__ s_i, const float* __restrict__ s_j,
                       int* __restrict__ cursor,
                       int* __restrict__ edge_src, float* __restrict__ edge_alpha)
{
    int i = blockIdx.x * blockDim.x + threadIdx.x;
    if (i < E) {
        int d = dst[i], s = src[i];
        float a = s_i[d] + s_j[s];
        a = (a > 0.f) ? a : 0.2f * a;
        int p = atomicAdd(&cursor[d], 1);
        edge_src[p] = s;
        edge_alpha[p] = a;
    } else if (i < E + N) {
        int n = i - E;
        float a = s_i[n] + s_j[n];
        a = (a > 0.f) ? a : 0.2f * a;
        int p = atomicAdd(&cursor[n], 1);
        edge_src[p] = n;
        edge_alpha[p] = a;
    }
}

// ---------------------------------------------------------------------------
// Per-node softmax + aggregate. One wave per node.
// Pass A: coalesced edge_alpha reads, lane-parallel online max+sum.
// Pass B: 4 edges x 16 lanes; each lane owns 4 channels (ushort4 bf16 row
// segment, 8B/lane); xor-reduce over lane bits 4-5 at the end.
// ---------------------------------------------------------------------------
__global__ __launch_bounds__(256) void k_aggregate(
    const unsigned short* __restrict__ g_bf,
    const int* __restrict__ row_ptr, const int* __restrict__ edge_src,
    const float* __restrict__ edge_alpha,
    const float* __restrict__ bias, float* __restrict__ out, int N)
{
    int wave = threadIdx.x >> 6, lane = threadIdx.x & 63;
    int n = blockIdx.x * 4 + wave;
    if (n >= N) return;

    int start = row_ptr[n];
    int end   = row_ptr[n + 1];

    // --- pass A: online max + expsum over coalesced alpha ---
    float m = -1e30f, ssum = 0.f;
    for (int e0 = start; e0 < end; e0 += 64) {
        int e = e0 + lane;
        if (e < end) {
            float a = edge_alpha[e];
            float nm = fmaxf(m, a);
            ssum = ssum * __expf(m - nm) + __expf(a - nm);
            m = nm;
        }
    }
#pragma unroll
    for (int o = 32; o > 0; o >>= 1) {
        float mo = __shfl_xor(m, o);
        float so = __shfl_xor(ssum, o);
        float nm = fmaxf(m, mo);
        ssum = ssum * __expf(m - nm) + so * __expf(mo - nm);
        m = nm;
    }
    float inv_denom = 1.f / (ssum + 1e-16f);

    // --- pass B: 4 edges in parallel, 16 lanes x 4 channels each ---
    int grp = lane >> 4;          // edge slot 0..3
    int cl  = lane & 15;          // channel group; owns ch {cl, cl+16, cl+32, cl+48}
    float a0 = 0.f, a1 = 0.f, a2 = 0.f, a3 = 0.f;
#pragma unroll 2
    for (int e0 = start; e0 < end; e0 += 4) {
        int e = e0 + grp;
        if (e < end) {
            float al  = edge_alpha[e];
            int  srcn = edge_src[e];
            float w = __expf(al - m) * inv_denom;
            ushort4 gv = *(const ushort4*)(g_bf + (size_t)srcn * C_DIM + (cl << 2));
            a0 = fmaf(w, bf2f(gv.x), a0);
            a1 = fmaf(w, bf2f(gv.y), a1);
            a2 = fmaf(w, bf2f(gv.z), a2);
            a3 = fmaf(w, bf2f(gv.w), a3);
        }
    }
    // reduce across the 4 edge groups (lane bits 4 and 5)
#pragma unroll
    for (int o = 16; o < 64; o <<= 1) {
        a0 += __shfl_xor(a0, o);
        a1 += __shfl_xor(a1, o);
        a2 += __shfl_xor(a2, o);
        a3 += __shfl_xor(a3, o);
    }
    if (grp == 0) {
        // acc i corresponds to channel cl + i*16 (permuted g layout)
        float r0 = fmaxf(a0 + bias[cl],      0.f);
        float r1 = fmaxf(a1 + bias[cl + 16], 0.f);
        float r2 = fmaxf(a2 + bias[cl + 32], 0.f);
        float r3 = fmaxf(a3 + bias[cl + 48], 0.f);
        float* op = out + (size_t)n * C_DIM;
        op[cl]      = r0;
        op[cl + 16] = r1;
        op[cl + 32] = r2;
        op[cl + 48] = r3;
    }
}

// ---------------------------------------------------------------------------
extern "C" void kernel_launch(void* const* d_in, const int* in_sizes, int n_in,
                              void* d_out, int out_size, void* d_ws, size_t ws_size,
                              hipStream_t stream)
{
    const float* x        = (const float*)d_in[0];
    const int*   eidx     = (const int*)  d_in[1];
    const float* corrs    = (const float*)d_in[2];
    const float* W        = (const float*)d_in[3];
    const float* att_i    = (const float*)d_in[4];
    const float* att_j    = (const float*)d_in[5];
    const float* att_em_i = (const float*)d_in[6];
    const float* att_em_j = (const float*)d_in[7];
    const float* bias     = (const float*)d_in[8];
    float* out = (float*)d_out;

    int N = in_sizes[0] / IN_DIM;
    int E = in_sizes[1] / 2;
    const int* src = eidx;
    const int* dst = eidx + E;

    char* ws = (char*)d_ws;
    size_t off = 0;
    auto alloc = [&](size_t bytes) -> void* {
        void* p = ws + off;
        off += (bytes + 255) & ~(size_t)255;
        return p;
    };
    unsigned short* g_bf     = (unsigned short*)alloc((size_t)N * C_DIM * sizeof(unsigned short));
    float* s_i      = (float*)alloc((size_t)N * sizeof(float));
    float* s_j      = (float*)alloc((size_t)N * sizeof(float));
    int*   deg      = (int*)  alloc((size_t)N * sizeof(int));
    int*   row_ptr  = (int*)  alloc((size_t)(N + 1) * sizeof(int));
    int*   cursor   = (int*)  alloc((size_t)N * sizeof(int));
    int*   edge_src = (int*)  alloc((size_t)(E + N) * sizeof(int));
    float* edge_alpha = (float*)alloc((size_t)(E + N) * sizeof(float));
    int    nb       = (N + 1023) / 1024;
    int*   bsum     = (int*)  alloc((size_t)nb * sizeof(int));
    (void)ws_size; (void)n_in; (void)out_size;

    k_mfma_scores<<<(N + 63) / 64, 256, 0, stream>>>(
        x, W, corrs, att_i, att_j, att_em_i, att_em_j, g_bf, s_i, s_j, N);

    k_init_deg  <<<(N + 255) / 256, 256, 0, stream>>>(deg, N);
    k_count     <<<(E + 255) / 256, 256, 0, stream>>>(dst, E, deg);
    k_scan_part <<<nb, 256, 0, stream>>>(deg, bsum, N);
    k_scan_bsum <<<1, 64, 0, stream>>>(bsum, nb, row_ptr + N);
    k_scan_final<<<nb, 256, 0, stream>>>(deg, bsum, row_ptr, cursor, N);
    k_fill      <<<(E + N + 255) / 256, 256, 0, stream>>>(
        src, dst, E, N, s_i, s_j, cursor, edge_src, edge_alpha);

    k_aggregate<<<(N + 3) / 4, 256, 0, stream>>>(
        g_bf, row_ptr, edge_src, edge_alpha, bias, out, N);
}

// Round 6
// 152.537 us; speedup vs baseline: 2.6578x; 1.0393x over previous
//
#include <hip/hip_runtime.h>
#include <hip/hip_bf16.h>
#include <math.h>

#define IN_DIM 128
#define C_DIM 64

typedef short bf16x8 __attribute__((ext_vector_type(8)));
typedef float f32x4 __attribute__((ext_vector_type(4)));

static __device__ __forceinline__ unsigned short f2bf(float f) {
    unsigned int u = __float_as_uint(f);
    u += 0x7FFFu + ((u >> 16) & 1u);          // round-to-nearest-even
    return (unsigned short)(u >> 16);
}
static __device__ __forceinline__ float bf2f(unsigned short h) {
    return __uint_as_float(((unsigned int)h) << 16);
}

// ---------------------------------------------------------------------------
// Kernel 1: g = x @ W via bf16 MFMA (3-term split), fused score dots.
// g stored as bf16 in PERMUTED channel layout: g_bf[row*64 + mrow*4 + t]
// holds channel (t*16 + mrow).
// ---------------------------------------------------------------------------
__global__ __launch_bounds__(256) void k_mfma_scores(
    const float* __restrict__ x, const float* __restrict__ W,
    const float* __restrict__ corrs,
    const float* __restrict__ att_i, const float* __restrict__ att_j,
    const float* __restrict__ att_em_i, const float* __restrict__ att_em_j,
    unsigned short* __restrict__ g_bf, float* __restrict__ s_i, float* __restrict__ s_j,
    int N)
{
    __shared__ __attribute__((aligned(16))) unsigned short WT[2][64][128]; // 32KB

    int tid = threadIdx.x;
#pragma unroll
    for (int p = 0; p < 8; ++p) {
        int f = p * 1024 + tid * 4;               // flat into W[128][64]
        f32x4 w4 = *(const f32x4*)(W + f);
        int k  = f >> 6;
        int c0 = f & 63;
#pragma unroll
        for (int i = 0; i < 4; ++i) {
            int c = c0 + i;
            float wv = w4[i];
            unsigned short hi = f2bf(wv);
            unsigned short lo = f2bf(wv - bf2f(hi));
            int ks = k ^ ((c & 7) << 3);
            WT[0][c][ks] = hi;
            WT[1][c][ks] = lo;
        }
    }
    __syncthreads();

    int wv = tid >> 6, lane = tid & 63;
    int mrow = lane & 15;
    int kgrp = lane >> 4;
    int row  = blockIdx.x * 64 + wv * 16 + mrow;
    int rowc = min(row, N - 1);

    f32x4 acc[4];
#pragma unroll
    for (int t = 0; t < 4; ++t) { f32x4 z = {0.f, 0.f, 0.f, 0.f}; acc[t] = z; }

#pragma unroll
    for (int s = 0; s < 4; ++s) {
        const float* xp = x + (size_t)rowc * IN_DIM + s * 32 + kgrp * 8;
        f32x4 xa = *(const f32x4*)xp;
        f32x4 xb = *(const f32x4*)(xp + 4);
        bf16x8 ah, al;
#pragma unroll
        for (int i = 0; i < 4; ++i) {
            unsigned short h0 = f2bf(xa[i]);
            ah[i]     = (short)h0;
            al[i]     = (short)f2bf(xa[i] - bf2f(h0));
            unsigned short h1 = f2bf(xb[i]);
            ah[4 + i] = (short)h1;
            al[4 + i] = (short)f2bf(xb[i] - bf2f(h1));
        }
        int kbase = s * 32 + kgrp * 8;
#pragma unroll
        for (int t = 0; t < 4; ++t) {
            int c  = t * 16 + mrow;
            int ks = kbase ^ ((c & 7) << 3);
            bf16x8 bh = *(const bf16x8*)&WT[0][c][ks];
            bf16x8 bl = *(const bf16x8*)&WT[1][c][ks];
            acc[t] = __builtin_amdgcn_mfma_f32_16x16x32_bf16(ah, bh, acc[t], 0, 0, 0);
            acc[t] = __builtin_amdgcn_mfma_f32_16x16x32_bf16(ah, bl, acc[t], 0, 0, 0);
            acc[t] = __builtin_amdgcn_mfma_f32_16x16x32_bf16(al, bh, acc[t], 0, 0, 0);
        }
    }

    float ai[4], aj[4], aei[4], aej[4];
#pragma unroll
    for (int t = 0; t < 4; ++t) {
        ai[t]  = att_i[t * 16 + mrow];
        aj[t]  = att_j[t * 16 + mrow];
        aei[t] = att_em_i[t * 16 + mrow];
        aej[t] = att_em_j[t * 16 + mrow];
    }
    int crow_base = blockIdx.x * 64 + wv * 16 + (lane >> 4) * 4;
#pragma unroll
    for (int r = 0; r < 4; ++r) {
        int grow  = crow_base + r;
        int growc = min(grow, N - 1);
        float vi = 0.f, vj = 0.f;
        ushort4 hv;
#pragma unroll
        for (int t = 0; t < 4; ++t) {
            float gv = acc[t][r];
            float cv = corrs[(size_t)growc * 64 + t * 16 + mrow];
            unsigned short h = f2bf(gv);
            if (t == 0) hv.x = h; else if (t == 1) hv.y = h;
            else if (t == 2) hv.z = h; else hv.w = h;
            vi = fmaf(gv, ai[t], fmaf(cv, aei[t], vi));
            vj = fmaf(gv, aj[t], fmaf(cv, aej[t], vj));
        }
        if (grow < N)
            *(ushort4*)(g_bf + (size_t)grow * C_DIM + mrow * 4) = hv;
#pragma unroll
        for (int o = 1; o < 16; o <<= 1) {
            vi += __shfl_xor(vi, o);
            vj += __shfl_xor(vj, o);
        }
        if (mrow == 0 && grow < N) { s_i[grow] = vi; s_j[grow] = vj; }
    }
}

// ---------------------------------------------------------------------------
// CSR build: deg init (=1 self loop), count, hierarchical scan, fill
// ---------------------------------------------------------------------------
__global__ void k_init_deg(int* __restrict__ deg, int N) {
    int i = blockIdx.x * blockDim.x + threadIdx.x;
    if (i < N) deg[i] = 1;
}

__global__ void k_count(const int* __restrict__ dst, int E, int* __restrict__ deg) {
    int i = blockIdx.x * blockDim.x + threadIdx.x;
    if (i < E) atomicAdd(&deg[dst[i]], 1);
}

__global__ __launch_bounds__(256) void k_scan_part(
    const int* __restrict__ deg, int* __restrict__ bsum, int N)
{
    int b = blockIdx.x, t = threadIdx.x;
    int base = b * 1024 + t * 4;
    int s = 0;
    if (base + 3 < N) {
        const int4 v = *(const int4*)(deg + base);
        s = v.x + v.y + v.z + v.w;
    } else {
        for (int i = 0; i < 4; ++i) if (base + i < N) s += deg[base + i];
    }
#pragma unroll
    for (int o = 1; o < 64; o <<= 1) s += __shfl_xor(s, o);
    __shared__ int ws[4];
    if ((t & 63) == 0) ws[t >> 6] = s;
    __syncthreads();
    if (t == 0) bsum[b] = ws[0] + ws[1] + ws[2] + ws[3];
}

__global__ void k_scan_bsum(int* __restrict__ bsum, int nb, int* __restrict__ rowptr_tail)
{
    int lane = threadIdx.x;
    int carry = 0;
    for (int b0 = 0; b0 < nb; b0 += 64) {
        int i = b0 + lane;
        int orig = (i < nb) ? bsum[i] : 0;
        int v = orig;
#pragma unroll
        for (int o = 1; o < 64; o <<= 1) {
            int u = __shfl_up(v, o);
            if (lane >= o) v += u;
        }
        if (i < nb) bsum[i] = carry + v - orig;   // exclusive
        carry += __shfl(v, 63);
    }
    if (lane == 0) *rowptr_tail = carry;          // row_ptr[N] = total
}

__global__ __launch_bounds__(256) void k_scan_final(
    const int* __restrict__ deg, const int* __restrict__ bsum,
    int* __restrict__ row_ptr, int* __restrict__ cursor, int N)
{
    int b = blockIdx.x, t = threadIdx.x;
    int base = b * 1024 + t * 4;
    int v[4];
    int s = 0;
#pragma unroll
    for (int i = 0; i < 4; ++i) {
        v[i] = (base + i < N) ? deg[base + i] : 0;
        s += v[i];
    }
    int lane = t & 63, wv = t >> 6;
    int inc = s;
#pragma unroll
    for (int o = 1; o < 64; o <<= 1) {
        int u = __shfl_up(inc, o);
        if (lane >= o) inc += u;
    }
    __shared__ int wsum[4];
    if (lane == 63) wsum[wv] = inc;
    __syncthreads();
    int woff = 0;
    for (int w = 0; w < wv; ++w) woff += wsum[w];
    int run = bsum[b] + woff + inc - s;            // exclusive prefix
#pragma unroll
    for (int i = 0; i < 4; ++i) {
        if (base + i < N) { row_ptr[base + i] = run; cursor[base + i] = run; }
        run += v[i];
    }
}

// Fill CSR slots: ONE scattered 8B nontemporal store per edge, packing
// (src int32 | alpha f32 bits). Halves dirtied lines vs two 4B scatters.
__global__ void k_fill(const int* __restrict__ src, const int* __restrict__ dst,
                       int E, int N,
                       const float* __restrict__ s_i, const float* __restrict__ s_j,
                       int* __restrict__ cursor,
                       long long* __restrict__ edge_rec)
{
    int i = blockIdx.x * blockDim.x + threadIdx.x;
    if (i < E) {
        int d = dst[i], s = src[i];
        float a = s_i[d] + s_j[s];
        a = (a > 0.f) ? a : 0.2f * a;
        int p = atomicAdd(&cursor[d], 1);
        long long rec = ((long long)__float_as_int(a) << 32) | (unsigned int)s;
        __builtin_nontemporal_store(rec, edge_rec + p);
    } else if (i < E + N) {
        int n = i - E;
        float a = s_i[n] + s_j[n];
        a = (a > 0.f) ? a : 0.2f * a;
        int p = atomicAdd(&cursor[n], 1);
        long long rec = ((long long)__float_as_int(a) << 32) | (unsigned int)n;
        __builtin_nontemporal_store(rec, edge_rec + p);
    }
}

// ---------------------------------------------------------------------------
// Per-node softmax + aggregate. One wave per node.
// Pass A: coalesced edge_rec reads (8B/lane), lane-parallel online max+sum.
// Pass B: 4 edges x 16 lanes; each lane owns 4 channels (ushort4 bf16, 8B).
// ---------------------------------------------------------------------------
__global__ __launch_bounds__(256) void k_aggregate(
    const unsigned short* __restrict__ g_bf,
    const int* __restrict__ row_ptr, const long long* __restrict__ edge_rec,
    const float* __restrict__ bias, float* __restrict__ out, int N)
{
    int wave = threadIdx.x >> 6, lane = threadIdx.x & 63;
    int n = blockIdx.x * 4 + wave;
    if (n >= N) return;

    int start = row_ptr[n];
    int end   = row_ptr[n + 1];

    // --- pass A: online max + expsum over coalesced records ---
    float m = -1e30f, ssum = 0.f;
    for (int e0 = start; e0 < end; e0 += 64) {
        int e = e0 + lane;
        if (e < end) {
            long long rec = edge_rec[e];
            float a = __int_as_float((int)(rec >> 32));
            float nm = fmaxf(m, a);
            ssum = ssum * __expf(m - nm) + __expf(a - nm);
            m = nm;
        }
    }
#pragma unroll
    for (int o = 32; o > 0; o >>= 1) {
        float mo = __shfl_xor(m, o);
        float so = __shfl_xor(ssum, o);
        float nm = fmaxf(m, mo);
        ssum = ssum * __expf(m - nm) + so * __expf(mo - nm);
        m = nm;
    }
    float inv_denom = 1.f / (ssum + 1e-16f);

    // --- pass B: 4 edges in parallel, 16 lanes x 4 channels each ---
    int grp = lane >> 4;          // edge slot 0..3
    int cl  = lane & 15;          // channel group; owns ch {cl, cl+16, cl+32, cl+48}
    float a0 = 0.f, a1 = 0.f, a2 = 0.f, a3 = 0.f;
#pragma unroll 2
    for (int e0 = start; e0 < end; e0 += 4) {
        int e = e0 + grp;
        if (e < end) {
            long long rec = edge_rec[e];           // broadcast within 16-lane group
            int   srcn = (int)(unsigned int)(rec & 0xFFFFFFFFu);
            float al   = __int_as_float((int)(rec >> 32));
            float w = __expf(al - m) * inv_denom;
            ushort4 gv = *(const ushort4*)(g_bf + (size_t)srcn * C_DIM + (cl << 2));
            a0 = fmaf(w, bf2f(gv.x), a0);
            a1 = fmaf(w, bf2f(gv.y), a1);
            a2 = fmaf(w, bf2f(gv.z), a2);
            a3 = fmaf(w, bf2f(gv.w), a3);
        }
    }
    // reduce across the 4 edge groups (lane bits 4 and 5)
#pragma unroll
    for (int o = 16; o < 64; o <<= 1) {
        a0 += __shfl_xor(a0, o);
        a1 += __shfl_xor(a1, o);
        a2 += __shfl_xor(a2, o);
        a3 += __shfl_xor(a3, o);
    }
    if (grp == 0) {
        float r0 = fmaxf(a0 + bias[cl],      0.f);
        float r1 = fmaxf(a1 + bias[cl + 16], 0.f);
        float r2 = fmaxf(a2 + bias[cl + 32], 0.f);
        float r3 = fmaxf(a3 + bias[cl + 48], 0.f);
        float* op = out + (size_t)n * C_DIM;
        op[cl]      = r0;
        op[cl + 16] = r1;
        op[cl + 32] = r2;
        op[cl + 48] = r3;
    }
}

// ---------------------------------------------------------------------------
extern "C" void kernel_launch(void* const* d_in, const int* in_sizes, int n_in,
                              void* d_out, int out_size, void* d_ws, size_t ws_size,
                              hipStream_t stream)
{
    const float* x        = (const float*)d_in[0];
    const int*   eidx     = (const int*)  d_in[1];
    const float* corrs    = (const float*)d_in[2];
    const float* W        = (const float*)d_in[3];
    const float* att_i    = (const float*)d_in[4];
    const float* att_j    = (const float*)d_in[5];
    const float* att_em_i = (const float*)d_in[6];
    const float* att_em_j = (const float*)d_in[7];
    const float* bias     = (const float*)d_in[8];
    float* out = (float*)d_out;

    int N = in_sizes[0] / IN_DIM;
    int E = in_sizes[1] / 2;
    const int* src = eidx;
    const int* dst = eidx + E;

    char* ws = (char*)d_ws;
    size_t off = 0;
    auto alloc = [&](size_t bytes) -> void* {
        void* p = ws + off;
        off += (bytes + 255) & ~(size_t)255;
        return p;
    };
    unsigned short* g_bf = (unsigned short*)alloc((size_t)N * C_DIM * sizeof(unsigned short));
    float* s_i      = (float*)alloc((size_t)N * sizeof(float));
    float* s_j      = (float*)alloc((size_t)N * sizeof(float));
    int*   deg      = (int*)  alloc((size_t)N * sizeof(int));
    int*   row_ptr  = (int*)  alloc((size_t)(N + 1) * sizeof(int));
    int*   cursor   = (int*)  alloc((size_t)N * sizeof(int));
    long long* edge_rec = (long long*)alloc((size_t)(E + N) * sizeof(long long));
    int    nb       = (N + 1023) / 1024;
    int*   bsum     = (int*)  alloc((size_t)nb * sizeof(int));
    (void)ws_size; (void)n_in; (void)out_size;

    k_mfma_scores<<<(N + 63) / 64, 256, 0, stream>>>(
        x, W, corrs, att_i, att_j, att_em_i, att_em_j, g_bf, s_i, s_j, N);

    k_init_deg  <<<(N + 255) / 256, 256, 0, stream>>>(deg, N);
    k_count     <<<(E + 255) / 256, 256, 0, stream>>>(dst, E, deg);
    k_scan_part <<<nb, 256, 0, stream>>>(deg, bsum, N);
    k_scan_bsum <<<1, 64, 0, stream>>>(bsum, nb, row_ptr + N);
    k_scan_final<<<nb, 256, 0, stream>>>(deg, bsum, row_ptr, cursor, N);
    k_fill      <<<(E + N + 255) / 256, 256, 0, stream>>>(
        src, dst, E, N, s_i, s_j, cursor, edge_rec);

    k_aggregate<<<(N + 3) / 4, 256, 0, stream>>>(
        g_bf, row_ptr, edge_rec, bias, out, N);
}